// Round 1
// baseline (274.435 us; speedup 1.0000x reference)
//
#include <hip/hip_runtime.h>
#include <stdint.h>

typedef unsigned short u16;
typedef unsigned int u32;
typedef __attribute__((ext_vector_type(8))) short short8;
typedef __attribute__((ext_vector_type(4))) float floatx4;

__device__ __forceinline__ u16 f2b(float f) {
  union { float f; u32 u; } c; c.f = f;
  u32 u = c.u;
  u += 0x7fffu + ((u >> 16) & 1u);
  return (u16)(u >> 16);
}
__device__ __forceinline__ float b2f(u16 h) {
  union { u32 u; float f; } c; c.u = ((u32)h) << 16;
  return c.f;
}

// ---------------- elementwise cast fp32 -> bf16 ----------------
__global__ void cast_bf16_k(const float* __restrict__ in, u16* __restrict__ out, int n) {
  int i = blockIdx.x * 256 + threadIdx.x;
  if (i < n) out[i] = f2b(in[i]);
}

// ---------------- tiled transpose+cast: [B][C][N] fp32 -> [B][N][C] bf16 ----------------
__global__ void transpose_cast_k(const float* __restrict__ in, u16* __restrict__ out, int C, int N) {
  __shared__ u16 tile[64][72];  // [n][c], stride 72 keeps 16B alignment for uint4 reads
  int b = blockIdx.z;
  int c0 = blockIdx.y * 64, n0 = blockIdx.x * 64;
  const float* src = in + ((size_t)b * C + c0) * N + n0;
  int t = threadIdx.x;
#pragma unroll
  for (int i = 0; i < 4; i++) {
    int id = t + i * 256;          // 0..1023
    int c = id >> 4, nq = (id & 15) * 4;
    float4 v = *(const float4*)(src + (size_t)c * N + nq);
    tile[nq + 0][c] = f2b(v.x);
    tile[nq + 1][c] = f2b(v.y);
    tile[nq + 2][c] = f2b(v.z);
    tile[nq + 3][c] = f2b(v.w);
  }
  __syncthreads();
  int n = t >> 2, ch = (t & 3) * 16;
  u16* dst = out + ((size_t)b * N + n0 + n) * C + c0 + ch;
  uint4 a = *(const uint4*)&tile[n][ch];
  uint4 bb = *(const uint4*)&tile[n][ch + 8];
  *(uint4*)dst = a;
  *(uint4*)(dst + 8) = bb;
}

// ---------------- argmin over M, split into 4 quarters ----------------
__global__ void argmin_part_k(const float* __restrict__ xyz1, const float* __restrict__ xyz2,
                              float2* __restrict__ cand) {
  __shared__ float4 s2[512];
  int b = blockIdx.z, mq = blockIdx.y, nq = blockIdx.x;
  const float* x2 = xyz2 + ((size_t)b * 2048 + mq * 512) * 3;
  for (int i = threadIdx.x; i < 512; i += 256)
    s2[i] = make_float4(x2[i * 3], x2[i * 3 + 1], x2[i * 3 + 2], 0.f);
  __syncthreads();
  int n = nq * 256 + threadIdx.x;
  const float* p1 = xyz1 + ((size_t)b * 8192 + n) * 3;
  float x = p1[0], y = p1[1], z = p1[2];
  float best = 3.0e38f; int bi = 0;
#pragma unroll 4
  for (int m = 0; m < 512; m++) {
    float4 q = s2[m];
    float dx = x - q.x, dy = y - q.y, dz = z - q.z;
    float d = dx * dx + dy * dy + dz * dz;
    if (d < best) { best = d; bi = m; }   // strict < keeps first occurrence
  }
  cand[(size_t)mq * 65536 + (size_t)b * 8192 + n] = make_float2(best, __int_as_float(mq * 512 + bi));
}

__global__ void argmin_combine_k(const float2* __restrict__ cand, int* __restrict__ idx) {
  int p = blockIdx.x * 256 + threadIdx.x;
  float bd = 3.0e38f; int bi = 0;
#pragma unroll
  for (int q = 0; q < 4; q++) {
    float2 c = cand[(size_t)q * 65536 + p];
    if (c.x < bd) { bd = c.x; bi = __float_as_int(c.y); }  // strict <: lower quarter wins ties
  }
  idx[p] = bi;
}

// ---------------- GEMM1: y0[p][o] = sum_k w0[o][k] * x[p][k], x = concat(f1t, gather(f2t, idx)) ----------------
__global__ __launch_bounds__(256) void gemm1_k(const u16* __restrict__ w0b, const u16* __restrict__ f1t,
                                               const u16* __restrict__ f2t, const int* __restrict__ idx,
                                               u16* __restrict__ y0) {
  __shared__ u16 As[128 * 72];
  __shared__ u16 Bs[128 * 72];
  __shared__ int sidx[128];
  int t = threadIdx.x;
  int pt0 = blockIdx.x * 128;
  int o0 = blockIdx.y * 128;
  int b = pt0 >> 13;
  if (t < 128) sidx[t] = idx[pt0 + t];
  floatx4 zero = {0.f, 0.f, 0.f, 0.f};
  floatx4 acc[4][4];
#pragma unroll
  for (int i = 0; i < 4; i++)
#pragma unroll
    for (int j = 0; j < 4; j++) acc[i][j] = zero;
  int lane = t & 63, wave = t >> 6;
  int wrow = (wave >> 1) * 64, wcol = (wave & 1) * 64;
  int lr = lane & 15, lq = lane >> 4;

  for (int k0 = 0; k0 < 384; k0 += 64) {
    __syncthreads();
#pragma unroll
    for (int i = 0; i < 4; i++) {
      int id = t + i * 256;
      int row = id >> 3, ch = (id & 7) * 8;
      *(uint4*)&As[row * 72 + ch] = *(const uint4*)(w0b + (size_t)(o0 + row) * 384 + k0 + ch);
    }
    if (k0 < 128) {
#pragma unroll
      for (int i = 0; i < 4; i++) {
        int id = t + i * 256;
        int row = id >> 3, ch = (id & 7) * 8;
        *(uint4*)&Bs[row * 72 + ch] = *(const uint4*)(f1t + (size_t)(pt0 + row) * 128 + k0 + ch);
      }
    } else {
#pragma unroll
      for (int i = 0; i < 4; i++) {
        int id = t + i * 256;
        int row = id >> 3, ch = (id & 7) * 8;
        *(uint4*)&Bs[row * 72 + ch] =
            *(const uint4*)(f2t + ((size_t)(b << 11) + sidx[row]) * 256 + (k0 - 128) + ch);
      }
    }
    __syncthreads();
#pragma unroll
    for (int ks = 0; ks < 2; ks++) {
      int kk = ks * 32 + lq * 8;
      short8 af[4], bf[4];
#pragma unroll
      for (int i = 0; i < 4; i++) af[i] = *(const short8*)&As[(wrow + i * 16 + lr) * 72 + kk];
#pragma unroll
      for (int j = 0; j < 4; j++) bf[j] = *(const short8*)&Bs[(wcol + j * 16 + lr) * 72 + kk];
#pragma unroll
      for (int i = 0; i < 4; i++)
#pragma unroll
        for (int j = 0; j < 4; j++)
          acc[i][j] = __builtin_amdgcn_mfma_f32_16x16x32_bf16(af[i], bf[j], acc[i][j], 0, 0, 0);
    }
  }
#pragma unroll
  for (int i = 0; i < 4; i++) {
#pragma unroll
    for (int j = 0; j < 4; j++) {
      int o = o0 + wrow + i * 16 + lq * 4;
      int p = pt0 + wcol + j * 16 + lr;
      uint2 pk;
      pk.x = (u32)f2b(acc[i][j][0]) | ((u32)f2b(acc[i][j][1]) << 16);
      pk.y = (u32)f2b(acc[i][j][2]) | ((u32)f2b(acc[i][j][3]) << 16);
      *(uint2*)&y0[(size_t)p * 256 + o] = pk;
    }
  }
}

// ---------------- GEMM2: y1[p][o] = sum_k w1[o][k] * relu(scale0[k]*y0[p][k]+shift0[k]) ----------------
__global__ __launch_bounds__(256) void gemm2_k(const u16* __restrict__ w1b, const u16* __restrict__ y0,
                                               const float* __restrict__ scale0, const float* __restrict__ shift0,
                                               u16* __restrict__ y1) {
  __shared__ u16 As[128 * 72];
  __shared__ u16 Bs[128 * 72];
  __shared__ float ssc[256], ssh[256];
  int t = threadIdx.x;
  ssc[t] = scale0[t];
  ssh[t] = shift0[t];
  int pt0 = blockIdx.x * 128;
  int o0 = blockIdx.y * 128;
  floatx4 zero = {0.f, 0.f, 0.f, 0.f};
  floatx4 acc[4][4];
#pragma unroll
  for (int i = 0; i < 4; i++)
#pragma unroll
    for (int j = 0; j < 4; j++) acc[i][j] = zero;
  int lane = t & 63, wave = t >> 6;
  int wrow = (wave >> 1) * 64, wcol = (wave & 1) * 64;
  int lr = lane & 15, lq = lane >> 4;

  for (int k0 = 0; k0 < 256; k0 += 64) {
    __syncthreads();
#pragma unroll
    for (int i = 0; i < 4; i++) {
      int id = t + i * 256;
      int row = id >> 3, ch = (id & 7) * 8;
      *(uint4*)&As[row * 72 + ch] = *(const uint4*)(w1b + (size_t)(o0 + row) * 256 + k0 + ch);
    }
#pragma unroll
    for (int i = 0; i < 4; i++) {
      int id = t + i * 256;
      int row = id >> 3, ch = (id & 7) * 8;
      uint4 raw = *(const uint4*)(y0 + (size_t)(pt0 + row) * 256 + k0 + ch);
      u32 rw[4] = {raw.x, raw.y, raw.z, raw.w};
      u32 ow[4];
#pragma unroll
      for (int w = 0; w < 4; w++) {
        int k = k0 + ch + w * 2;
        float v0 = b2f((u16)(rw[w] & 0xffffu));
        float v1 = b2f((u16)(rw[w] >> 16));
        v0 = fmaxf(v0 * ssc[k] + ssh[k], 0.f);
        v1 = fmaxf(v1 * ssc[k + 1] + ssh[k + 1], 0.f);
        ow[w] = (u32)f2b(v0) | ((u32)f2b(v1) << 16);
      }
      uint4 ov; ov.x = ow[0]; ov.y = ow[1]; ov.z = ow[2]; ov.w = ow[3];
      *(uint4*)&Bs[row * 72 + ch] = ov;
    }
    __syncthreads();
#pragma unroll
    for (int ks = 0; ks < 2; ks++) {
      int kk = ks * 32 + lq * 8;
      short8 af[4], bf[4];
#pragma unroll
      for (int i = 0; i < 4; i++) af[i] = *(const short8*)&As[(wrow + i * 16 + lr) * 72 + kk];
#pragma unroll
      for (int j = 0; j < 4; j++) bf[j] = *(const short8*)&Bs[(wcol + j * 16 + lr) * 72 + kk];
#pragma unroll
      for (int i = 0; i < 4; i++)
#pragma unroll
        for (int j = 0; j < 4; j++)
          acc[i][j] = __builtin_amdgcn_mfma_f32_16x16x32_bf16(af[i], bf[j], acc[i][j], 0, 0, 0);
    }
  }
#pragma unroll
  for (int i = 0; i < 4; i++) {
#pragma unroll
    for (int j = 0; j < 4; j++) {
      int o = o0 + wrow + i * 16 + lq * 4;
      int p = pt0 + wcol + j * 16 + lr;
      uint2 pk;
      pk.x = (u32)f2b(acc[i][j][0]) | ((u32)f2b(acc[i][j][1]) << 16);
      pk.y = (u32)f2b(acc[i][j][2]) | ((u32)f2b(acc[i][j][3]) << 16);
      *(uint2*)&y1[(size_t)p * 256 + o] = pk;
    }
  }
}

// ---------------- per-channel sums over [p][256] bf16 ----------------
__global__ void stats_k(const u16* __restrict__ y, float* __restrict__ sum, float* __restrict__ sq) {
  int o = threadIdx.x;
  const u16* base = y + (size_t)blockIdx.x * 65536 + o;  // 256 pts x 256 ch per block
  float s = 0.f, q = 0.f;
  for (int p = 0; p < 256; p++) {
    float v = b2f(base[(size_t)p * 256]);
    s += v; q += v * v;
  }
  atomicAdd(&sum[o], s);
  atomicAdd(&sq[o], q);
}

__global__ void bnparam_k(const float* __restrict__ sum, const float* __restrict__ sq,
                          const float* __restrict__ gamma, const float* __restrict__ beta,
                          float* __restrict__ scale, float* __restrict__ shift) {
  int o = threadIdx.x;
  float mean = sum[o] * (1.f / 65536.f);
  float var = sq[o] * (1.f / 65536.f) - mean * mean;
  var = fmaxf(var, 0.f);
  float r = rsqrtf(var + 1e-5f);
  float sc = gamma[o] * r;
  scale[o] = sc;
  shift[o] = beta[o] - mean * sc;
}

// ---------------- finalize: BN1+ReLU + transpose [p][o] bf16 -> [b][o][n] fp32 ----------------
__global__ void finalize_k(const u16* __restrict__ y1, const float* __restrict__ scale,
                           const float* __restrict__ shift, float* __restrict__ out) {
  __shared__ float tile[64][65];
  int b = blockIdx.z, o0 = blockIdx.y * 64, n0 = blockIdx.x * 64;
  int t = threadIdx.x;
  int pl = t >> 2, ch = (t & 3) * 16;
  const u16* src = y1 + ((size_t)(b * 8192 + n0 + pl)) * 256 + o0 + ch;
  uint4 r0 = *(const uint4*)src;
  uint4 r1 = *(const uint4*)(src + 8);
  u16 hv[16];
  *(uint4*)&hv[0] = r0;
  *(uint4*)&hv[8] = r1;
#pragma unroll
  for (int e = 0; e < 16; e++) {
    int o = o0 + ch + e;
    float v = b2f(hv[e]) * scale[o] + shift[o];
    tile[pl][ch + e] = fmaxf(v, 0.f);
  }
  __syncthreads();
  int ol = t >> 2, nch = (t & 3) * 16;
  float* dst = out + ((size_t)(b * 256 + o0 + ol)) * 8192 + n0 + nch;
#pragma unroll
  for (int j = 0; j < 16; j += 4) {
    float4 v = make_float4(tile[nch + j][ol], tile[nch + j + 1][ol],
                           tile[nch + j + 2][ol], tile[nch + j + 3][ol]);
    *(float4*)(dst + j) = v;
  }
}

extern "C" void kernel_launch(void* const* d_in, const int* in_sizes, int n_in,
                              void* d_out, int out_size, void* d_ws, size_t ws_size,
                              hipStream_t stream) {
  const float* xyz1      = (const float*)d_in[0];
  const float* xyz2      = (const float*)d_in[1];
  const float* features1 = (const float*)d_in[2];
  const float* features2 = (const float*)d_in[3];
  const float* conv_w0   = (const float*)d_in[4];
  const float* gamma0    = (const float*)d_in[5];
  const float* beta0     = (const float*)d_in[6];
  const float* conv_w1   = (const float*)d_in[7];
  const float* gamma1    = (const float*)d_in[8];
  const float* beta1     = (const float*)d_in[9];
  float* out = (float*)d_out;

  char* ws = (char*)d_ws;
  size_t off = 0;
  auto alloc = [&](size_t bytes) {
    char* p = ws + off;
    off = (off + bytes + 4095) & ~(size_t)4095;
    return p;
  };
  int*   idx    = (int*)alloc(65536 * 4);
  float* sums   = (float*)alloc(4 * 256 * 4);   // sum0, sq0, sum1, sq1
  float* params = (float*)alloc(4 * 256 * 4);   // scale0, shift0, scale1, shift1
  u16*   w0b    = (u16*)alloc(256 * 384 * 2);
  u16*   w1b    = (u16*)alloc(256 * 256 * 2);
  u16*   f1t    = (u16*)alloc((size_t)65536 * 128 * 2);
  u16*   f2t    = (u16*)alloc((size_t)16384 * 256 * 2);
  u16*   y0     = (u16*)alloc((size_t)65536 * 256 * 2);
  u16*   y1     = (u16*)alloc((size_t)65536 * 256 * 2);
  float2* cand  = (float2*)f1t;  // overlay: cand is dead before f1t is written

  hipMemsetAsync(sums, 0, 4 * 256 * 4, stream);
  cast_bf16_k<<<dim3(384), 256, 0, stream>>>(conv_w0, w0b, 98304);
  cast_bf16_k<<<dim3(256), 256, 0, stream>>>(conv_w1, w1b, 65536);
  argmin_part_k<<<dim3(32, 4, 8), 256, 0, stream>>>(xyz1, xyz2, cand);
  argmin_combine_k<<<dim3(256), 256, 0, stream>>>(cand, idx);
  transpose_cast_k<<<dim3(128, 2, 8), 256, 0, stream>>>(features1, f1t, 128, 8192);
  transpose_cast_k<<<dim3(32, 4, 8), 256, 0, stream>>>(features2, f2t, 256, 2048);
  gemm1_k<<<dim3(512, 2), 256, 0, stream>>>(w0b, f1t, f2t, idx, y0);
  stats_k<<<dim3(256), 256, 0, stream>>>(y0, sums + 0, sums + 256);
  bnparam_k<<<1, 256, 0, stream>>>(sums + 0, sums + 256, gamma0, beta0, params + 0, params + 256);
  gemm2_k<<<dim3(512, 2), 256, 0, stream>>>(w1b, y0, params + 0, params + 256, y1);
  stats_k<<<dim3(256), 256, 0, stream>>>(y1, sums + 512, sums + 768);
  bnparam_k<<<1, 256, 0, stream>>>(sums + 512, sums + 768, gamma1, beta1, params + 512, params + 768);
  finalize_k<<<dim3(128, 4, 8), 256, 0, stream>>>(y1, params + 512, params + 768, out);
}

// Round 2
// 268.700 us; speedup vs baseline: 1.0213x; 1.0213x over previous
//
#include <hip/hip_runtime.h>
#include <stdint.h>

typedef unsigned short u16;
typedef unsigned int u32;
typedef __attribute__((ext_vector_type(8))) short short8;
typedef __attribute__((ext_vector_type(4))) float floatx4;

__device__ __forceinline__ u16 f2b(float f) {
  union { float f; u32 u; } c; c.f = f;
  u32 u = c.u;
  u += 0x7fffu + ((u >> 16) & 1u);
  return (u16)(u >> 16);
}
__device__ __forceinline__ float b2f(u16 h) {
  union { u32 u; float f; } c; c.u = ((u32)h) << 16;
  return c.f;
}

// async global->LDS, 16B per lane; LDS dest must be wave-uniform (lane slot = base + lane*16)
__device__ __forceinline__ void glds16(const void* g, void* l) {
  __builtin_amdgcn_global_load_lds((__attribute__((address_space(1))) void*)g,
                                   (__attribute__((address_space(3))) void*)l, 16, 0, 0);
}

// ---------------- elementwise cast fp32 -> bf16 ----------------
__global__ void cast_bf16_k(const float* __restrict__ in, u16* __restrict__ out, int n) {
  int i = blockIdx.x * 256 + threadIdx.x;
  if (i < n) out[i] = f2b(in[i]);
}

// ---------------- tiled transpose+cast: [B][C][N] fp32 -> [B][N][C] bf16 ----------------
__global__ void transpose_cast_k(const float* __restrict__ in, u16* __restrict__ out, int C, int N) {
  __shared__ u16 tile[64][72];
  int b = blockIdx.z;
  int c0 = blockIdx.y * 64, n0 = blockIdx.x * 64;
  const float* src = in + ((size_t)b * C + c0) * N + n0;
  int t = threadIdx.x;
#pragma unroll
  for (int i = 0; i < 4; i++) {
    int id = t + i * 256;
    int c = id >> 4, nq = (id & 15) * 4;
    float4 v = *(const float4*)(src + (size_t)c * N + nq);
    tile[nq + 0][c] = f2b(v.x);
    tile[nq + 1][c] = f2b(v.y);
    tile[nq + 2][c] = f2b(v.z);
    tile[nq + 3][c] = f2b(v.w);
  }
  __syncthreads();
  int n = t >> 2, ch = (t & 3) * 16;
  u16* dst = out + ((size_t)b * N + n0 + n) * C + c0 + ch;
  uint4 a = *(const uint4*)&tile[n][ch];
  uint4 bb = *(const uint4*)&tile[n][ch + 8];
  *(uint4*)dst = a;
  *(uint4*)(dst + 8) = bb;
}

// ---------------- argmin: 4 query points per thread, M in 8 chunks of 256 ----------------
__global__ void argmin_part_k(const float* __restrict__ xyz1, const float* __restrict__ xyz2,
                              float2* __restrict__ cand) {
  __shared__ float4 s2[256];
  int b = blockIdx.z, mq = blockIdx.y, nq = blockIdx.x;
  const float* x2 = xyz2 + ((size_t)b * 2048 + mq * 256) * 3;
  int t = threadIdx.x;
  s2[t] = make_float4(x2[t * 3], x2[t * 3 + 1], x2[t * 3 + 2], 0.f);
  __syncthreads();
  int n0 = nq * 1024 + t;
  float px[4], py[4], pz[4];
#pragma unroll
  for (int q = 0; q < 4; q++) {
    const float* p1 = xyz1 + ((size_t)b * 8192 + n0 + q * 256) * 3;
    px[q] = p1[0]; py[q] = p1[1]; pz[q] = p1[2];
  }
  float best[4] = {3.0e38f, 3.0e38f, 3.0e38f, 3.0e38f};
  int bi[4] = {0, 0, 0, 0};
#pragma unroll 4
  for (int m = 0; m < 256; m++) {
    float4 qq = s2[m];
#pragma unroll
    for (int q = 0; q < 4; q++) {
      float dx = px[q] - qq.x, dy = py[q] - qq.y, dz = pz[q] - qq.z;
      float d = fmaf(dz, dz, fmaf(dy, dy, dx * dx));  // same contraction as round-1 (passing)
      bool c = d < best[q];
      best[q] = c ? d : best[q];
      bi[q] = c ? m : bi[q];
    }
  }
#pragma unroll
  for (int q = 0; q < 4; q++) {
    int n = n0 + q * 256;
    cand[(size_t)mq * 65536 + (size_t)b * 8192 + n] =
        make_float2(best[q], __int_as_float(mq * 256 + bi[q]));
  }
}

__global__ void argmin_combine_k(const float2* __restrict__ cand, int* __restrict__ idx) {
  int p = blockIdx.x * 256 + threadIdx.x;
  float bd = 3.0e38f; int bi = 0;
#pragma unroll
  for (int q = 0; q < 8; q++) {
    float2 c = cand[(size_t)q * 65536 + p];
    if (c.x < bd) { bd = c.x; bi = __float_as_int(c.y); }  // strict <: lower chunk wins ties
  }
  idx[p] = bi;
}

// ---------------- GEMM1: y0[p][o] = sum_k w0[o][k] * x[p][k]; async swizzled staging ----------------
__global__ __launch_bounds__(256) void gemm1_k(const u16* __restrict__ w0b, const u16* __restrict__ f1t,
                                               const u16* __restrict__ f2t, const int* __restrict__ idx,
                                               u16* __restrict__ y0) {
  __shared__ u16 As[128 * 64];  // rows of 64 u16 (128B), 16B-chunk XOR swizzle: phys = logical ^ (row&7)
  __shared__ u16 Bs[128 * 64];
  __shared__ int sidx[128];
  int t = threadIdx.x;
  int pt0 = blockIdx.x * 128, o0 = blockIdx.y * 128;
  int b = pt0 >> 13;
  if (t < 128) sidx[t] = idx[pt0 + t];
  floatx4 zero = {0.f, 0.f, 0.f, 0.f};
  floatx4 acc[4][4];
#pragma unroll
  for (int i = 0; i < 4; i++)
#pragma unroll
    for (int j = 0; j < 4; j++) acc[i][j] = zero;
  int lane = t & 63, wave = t >> 6;
  int wrow = (wave >> 1) * 64, wcol = (wave & 1) * 64;
  int lr = lane & 15, lq = lane >> 4;
  int srow = lane >> 3;                    // row within 8-row staging chunk
  int sch = ((lane & 7) ^ srow) * 8;       // swizzled source channel (u16 units)
  __syncthreads();
  int rowS[4], gidxB[4];
#pragma unroll
  for (int i = 0; i < 4; i++) {
    rowS[i] = (i * 4 + wave) * 8 + srow;
    gidxB[i] = sidx[rowS[i]];
  }

#pragma unroll
  for (int k0 = 0; k0 < 384; k0 += 64) {
    __syncthreads();
#pragma unroll
    for (int i = 0; i < 4; i++)
      glds16(w0b + (size_t)(o0 + rowS[i]) * 384 + k0 + sch, &As[(i * 4 + wave) * 512]);
    if (k0 < 128) {
#pragma unroll
      for (int i = 0; i < 4; i++)
        glds16(f1t + (size_t)(pt0 + rowS[i]) * 128 + k0 + sch, &Bs[(i * 4 + wave) * 512]);
    } else {
#pragma unroll
      for (int i = 0; i < 4; i++)
        glds16(f2t + ((size_t)(b << 11) + gidxB[i]) * 256 + (k0 - 128) + sch, &Bs[(i * 4 + wave) * 512]);
    }
    __syncthreads();
#pragma unroll
    for (int ks = 0; ks < 2; ks++) {
      short8 af[4], bf[4];
#pragma unroll
      for (int i = 0; i < 4; i++) {
        int row = wrow + i * 16 + lr;
        af[i] = *(const short8*)&As[row * 64 + ((((ks << 2) | lq) ^ (lr & 7)) << 3)];
      }
#pragma unroll
      for (int j = 0; j < 4; j++) {
        int row = wcol + j * 16 + lr;
        bf[j] = *(const short8*)&Bs[row * 64 + ((((ks << 2) | lq) ^ (lr & 7)) << 3)];
      }
#pragma unroll
      for (int i = 0; i < 4; i++)
#pragma unroll
        for (int j = 0; j < 4; j++)
          acc[i][j] = __builtin_amdgcn_mfma_f32_16x16x32_bf16(af[i], bf[j], acc[i][j], 0, 0, 0);
    }
  }
#pragma unroll
  for (int i = 0; i < 4; i++) {
#pragma unroll
    for (int j = 0; j < 4; j++) {
      int o = o0 + wrow + i * 16 + lq * 4;
      int p = pt0 + wcol + j * 16 + lr;
      uint2 pk;
      pk.x = (u32)f2b(acc[i][j][0]) | ((u32)f2b(acc[i][j][1]) << 16);
      pk.y = (u32)f2b(acc[i][j][2]) | ((u32)f2b(acc[i][j][3]) << 16);
      *(uint2*)&y0[(size_t)p * 256 + o] = pk;
    }
  }
}

// ---------------- GEMM2: y1[p][o] = sum_k w1[o][k] * relu(scale0[k]*y0[p][k]+shift0[k]) ----------------
__global__ __launch_bounds__(256) void gemm2_k(const u16* __restrict__ w1b, const u16* __restrict__ y0,
                                               const float* __restrict__ scale0, const float* __restrict__ shift0,
                                               u16* __restrict__ y1) {
  __shared__ u16 As[128 * 64];   // async swizzled
  __shared__ u16 Bs[128 * 72];   // register-staged (BN transform), padded
  __shared__ float ssc[256], ssh[256];
  int t = threadIdx.x;
  ssc[t] = scale0[t];
  ssh[t] = shift0[t];
  int pt0 = blockIdx.x * 128, o0 = blockIdx.y * 128;
  floatx4 zero = {0.f, 0.f, 0.f, 0.f};
  floatx4 acc[4][4];
#pragma unroll
  for (int i = 0; i < 4; i++)
#pragma unroll
    for (int j = 0; j < 4; j++) acc[i][j] = zero;
  int lane = t & 63, wave = t >> 6;
  int wrow = (wave >> 1) * 64, wcol = (wave & 1) * 64;
  int lr = lane & 15, lq = lane >> 4;
  int srow = lane >> 3;
  int sch = ((lane & 7) ^ srow) * 8;
  __syncthreads();  // ssc/ssh visible

#pragma unroll
  for (int k0 = 0; k0 < 256; k0 += 64) {
    __syncthreads();
#pragma unroll
    for (int i = 0; i < 4; i++) {
      int rowA = (i * 4 + wave) * 8 + srow;
      glds16(w1b + (size_t)(o0 + rowA) * 256 + k0 + sch, &As[(i * 4 + wave) * 512]);
    }
#pragma unroll
    for (int i = 0; i < 4; i++) {
      int id = t + i * 256;
      int row = id >> 3, ch = (id & 7) * 8;
      uint4 raw = *(const uint4*)(y0 + (size_t)(pt0 + row) * 256 + k0 + ch);
      u32 rw[4] = {raw.x, raw.y, raw.z, raw.w};
      u32 ow[4];
#pragma unroll
      for (int w = 0; w < 4; w++) {
        int k = k0 + ch + w * 2;
        float v0 = b2f((u16)(rw[w] & 0xffffu));
        float v1 = b2f((u16)(rw[w] >> 16));
        v0 = fmaxf(v0 * ssc[k] + ssh[k], 0.f);
        v1 = fmaxf(v1 * ssc[k + 1] + ssh[k + 1], 0.f);
        ow[w] = (u32)f2b(v0) | ((u32)f2b(v1) << 16);
      }
      uint4 ov; ov.x = ow[0]; ov.y = ow[1]; ov.z = ow[2]; ov.w = ow[3];
      *(uint4*)&Bs[row * 72 + ch] = ov;
    }
    __syncthreads();
#pragma unroll
    for (int ks = 0; ks < 2; ks++) {
      int kk = ks * 32 + lq * 8;
      short8 af[4], bf[4];
#pragma unroll
      for (int i = 0; i < 4; i++) {
        int row = wrow + i * 16 + lr;
        af[i] = *(const short8*)&As[row * 64 + ((((ks << 2) | lq) ^ (lr & 7)) << 3)];
      }
#pragma unroll
      for (int j = 0; j < 4; j++) bf[j] = *(const short8*)&Bs[(wcol + j * 16 + lr) * 72 + kk];
#pragma unroll
      for (int i = 0; i < 4; i++)
#pragma unroll
        for (int j = 0; j < 4; j++)
          acc[i][j] = __builtin_amdgcn_mfma_f32_16x16x32_bf16(af[i], bf[j], acc[i][j], 0, 0, 0);
    }
  }
#pragma unroll
  for (int i = 0; i < 4; i++) {
#pragma unroll
    for (int j = 0; j < 4; j++) {
      int o = o0 + wrow + i * 16 + lq * 4;
      int p = pt0 + wcol + j * 16 + lr;
      uint2 pk;
      pk.x = (u32)f2b(acc[i][j][0]) | ((u32)f2b(acc[i][j][1]) << 16);
      pk.y = (u32)f2b(acc[i][j][2]) | ((u32)f2b(acc[i][j][3]) << 16);
      *(uint2*)&y1[(size_t)p * 256 + o] = pk;
    }
  }
}

// ---------------- per-channel sums over [p][256] bf16 ----------------
__global__ void stats_k(const u16* __restrict__ y, float* __restrict__ sum, float* __restrict__ sq) {
  int o = threadIdx.x;
  const u16* base = y + (size_t)blockIdx.x * 65536 + o;
  float s = 0.f, q = 0.f;
  for (int p = 0; p < 256; p++) {
    float v = b2f(base[(size_t)p * 256]);
    s += v; q += v * v;
  }
  atomicAdd(&sum[o], s);
  atomicAdd(&sq[o], q);
}

__global__ void bnparam_k(const float* __restrict__ sum, const float* __restrict__ sq,
                          const float* __restrict__ gamma, const float* __restrict__ beta,
                          float* __restrict__ scale, float* __restrict__ shift) {
  int o = threadIdx.x;
  float mean = sum[o] * (1.f / 65536.f);
  float var = sq[o] * (1.f / 65536.f) - mean * mean;
  var = fmaxf(var, 0.f);
  float r = rsqrtf(var + 1e-5f);
  float sc = gamma[o] * r;
  scale[o] = sc;
  shift[o] = beta[o] - mean * sc;
}

// ---------------- finalize: BN1+ReLU + transpose [p][o] bf16 -> [b][o][n] fp32 ----------------
__global__ void finalize_k(const u16* __restrict__ y1, const float* __restrict__ scale,
                           const float* __restrict__ shift, float* __restrict__ out) {
  __shared__ float tile[64][65];
  int b = blockIdx.z, o0 = blockIdx.y * 64, n0 = blockIdx.x * 64;
  int t = threadIdx.x;
  int pl = t >> 2, ch = (t & 3) * 16;
  const u16* src = y1 + ((size_t)(b * 8192 + n0 + pl)) * 256 + o0 + ch;
  uint4 r0 = *(const uint4*)src;
  uint4 r1 = *(const uint4*)(src + 8);
  u16 hv[16];
  *(uint4*)&hv[0] = r0;
  *(uint4*)&hv[8] = r1;
#pragma unroll
  for (int e = 0; e < 16; e++) {
    int o = o0 + ch + e;
    float v = b2f(hv[e]) * scale[o] + shift[o];
    tile[pl][ch + e] = fmaxf(v, 0.f);
  }
  __syncthreads();
  int ol = t >> 2, nch = (t & 3) * 16;
  float* dst = out + ((size_t)(b * 256 + o0 + ol)) * 8192 + n0 + nch;
#pragma unroll
  for (int j = 0; j < 16; j += 4) {
    float4 v = make_float4(tile[nch + j][ol], tile[nch + j + 1][ol],
                           tile[nch + j + 2][ol], tile[nch + j + 3][ol]);
    *(float4*)(dst + j) = v;
  }
}

extern "C" void kernel_launch(void* const* d_in, const int* in_sizes, int n_in,
                              void* d_out, int out_size, void* d_ws, size_t ws_size,
                              hipStream_t stream) {
  const float* xyz1      = (const float*)d_in[0];
  const float* xyz2      = (const float*)d_in[1];
  const float* features1 = (const float*)d_in[2];
  const float* features2 = (const float*)d_in[3];
  const float* conv_w0   = (const float*)d_in[4];
  const float* gamma0    = (const float*)d_in[5];
  const float* beta0     = (const float*)d_in[6];
  const float* conv_w1   = (const float*)d_in[7];
  const float* gamma1    = (const float*)d_in[8];
  const float* beta1     = (const float*)d_in[9];
  float* out = (float*)d_out;

  char* ws = (char*)d_ws;
  size_t off = 0;
  auto alloc = [&](size_t bytes) {
    char* p = ws + off;
    off = (off + bytes + 4095) & ~(size_t)4095;
    return p;
  };
  int*   idx    = (int*)alloc(65536 * 4);
  float* sums   = (float*)alloc(4 * 256 * 4);
  float* params = (float*)alloc(4 * 256 * 4);
  u16*   w0b    = (u16*)alloc(256 * 384 * 2);
  u16*   w1b    = (u16*)alloc(256 * 256 * 2);
  u16*   f1t    = (u16*)alloc((size_t)65536 * 128 * 2);
  u16*   f2t    = (u16*)alloc((size_t)16384 * 256 * 2);
  u16*   y0     = (u16*)alloc((size_t)65536 * 256 * 2);
  u16*   y1     = (u16*)alloc((size_t)65536 * 256 * 2);
  float2* cand  = (float2*)f1t;  // overlay: cand dead before f1t written (stream-ordered)

  hipMemsetAsync(sums, 0, 4 * 256 * 4, stream);
  cast_bf16_k<<<dim3(384), 256, 0, stream>>>(conv_w0, w0b, 98304);
  cast_bf16_k<<<dim3(256), 256, 0, stream>>>(conv_w1, w1b, 65536);
  argmin_part_k<<<dim3(8, 8, 8), 256, 0, stream>>>(xyz1, xyz2, cand);
  argmin_combine_k<<<dim3(256), 256, 0, stream>>>(cand, idx);
  transpose_cast_k<<<dim3(128, 2, 8), 256, 0, stream>>>(features1, f1t, 128, 8192);
  transpose_cast_k<<<dim3(32, 4, 8), 256, 0, stream>>>(features2, f2t, 256, 2048);
  gemm1_k<<<dim3(512, 2), 256, 0, stream>>>(w0b, f1t, f2t, idx, y0);
  stats_k<<<dim3(256), 256, 0, stream>>>(y0, sums + 0, sums + 256);
  bnparam_k<<<1, 256, 0, stream>>>(sums + 0, sums + 256, gamma0, beta0, params + 0, params + 256);
  gemm2_k<<<dim3(512, 2), 256, 0, stream>>>(w1b, y0, params + 0, params + 256, y1);
  stats_k<<<dim3(256), 256, 0, stream>>>(y1, sums + 512, sums + 768);
  bnparam_k<<<1, 256, 0, stream>>>(sums + 512, sums + 768, gamma1, beta1, params + 512, params + 768);
  finalize_k<<<dim3(128, 4, 8), 256, 0, stream>>>(y1, params + 512, params + 768, out);
}

// Round 3
// 249.863 us; speedup vs baseline: 1.0983x; 1.0754x over previous
//
#include <hip/hip_runtime.h>
#include <stdint.h>

typedef unsigned short u16;
typedef unsigned int u32;
typedef __attribute__((ext_vector_type(8))) short short8;
typedef __attribute__((ext_vector_type(4))) float floatx4;

__device__ __forceinline__ u16 f2b(float f) {
  union { float f; u32 u; } c; c.f = f;
  u32 u = c.u;
  u += 0x7fffu + ((u >> 16) & 1u);
  return (u16)(u >> 16);
}
__device__ __forceinline__ float b2f(u16 h) {
  union { u32 u; float f; } c; c.u = ((u32)h) << 16;
  return c.f;
}

// async global->LDS, 16B per lane; LDS dest is wave-uniform base + lane*16
__device__ __forceinline__ void glds16(const void* g, void* l) {
  __builtin_amdgcn_global_load_lds((__attribute__((address_space(1))) void*)g,
                                   (__attribute__((address_space(3))) void*)l, 16, 0, 0);
}

// ---------------- prep: cast both weights to bf16 + zero the stats accumulators ----------------
__global__ void prep_k(const float* __restrict__ w0, const float* __restrict__ w1,
                       u16* __restrict__ w0b, u16* __restrict__ w1b, float* __restrict__ sums) {
  int blk = blockIdx.x, t = threadIdx.x;
  int i = blk * 256 + t;
  if (blk < 384) w0b[i] = f2b(w0[i]);
  else { int j = i - 98304; w1b[j] = f2b(w1[j]); }
  if (blk < 4) sums[i] = 0.f;
}

// ---------------- tiled transpose+cast: [B][C][N] fp32 -> [B][N][C] bf16 ----------------
__global__ void transpose_cast_k(const float* __restrict__ in, u16* __restrict__ out, int C, int N) {
  __shared__ u16 tile[64][72];
  int b = blockIdx.z;
  int c0 = blockIdx.y * 64, n0 = blockIdx.x * 64;
  const float* src = in + ((size_t)b * C + c0) * N + n0;
  int t = threadIdx.x;
#pragma unroll
  for (int i = 0; i < 4; i++) {
    int id = t + i * 256;
    int c = id >> 4, nq = (id & 15) * 4;
    float4 v = *(const float4*)(src + (size_t)c * N + nq);
    tile[nq + 0][c] = f2b(v.x);
    tile[nq + 1][c] = f2b(v.y);
    tile[nq + 2][c] = f2b(v.z);
    tile[nq + 3][c] = f2b(v.w);
  }
  __syncthreads();
  int n = t >> 2, ch = (t & 3) * 16;
  u16* dst = out + ((size_t)b * N + n0 + n) * C + c0 + ch;
  uint4 a = *(const uint4*)&tile[n][ch];
  uint4 bb = *(const uint4*)&tile[n][ch + 8];
  *(uint4*)dst = a;
  *(uint4*)(dst + 8) = bb;
}

// ---------------- argmin: 4 query points per thread, M in 8 chunks of 256 ----------------
__global__ void argmin_part_k(const float* __restrict__ xyz1, const float* __restrict__ xyz2,
                              float2* __restrict__ cand) {
  __shared__ float4 s2[256];
  int b = blockIdx.z, mq = blockIdx.y, nq = blockIdx.x;
  const float* x2 = xyz2 + ((size_t)b * 2048 + mq * 256) * 3;
  int t = threadIdx.x;
  s2[t] = make_float4(x2[t * 3], x2[t * 3 + 1], x2[t * 3 + 2], 0.f);
  __syncthreads();
  int n0 = nq * 1024 + t;
  float px[4], py[4], pz[4];
#pragma unroll
  for (int q = 0; q < 4; q++) {
    const float* p1 = xyz1 + ((size_t)b * 8192 + n0 + q * 256) * 3;
    px[q] = p1[0]; py[q] = p1[1]; pz[q] = p1[2];
  }
  float best[4] = {3.0e38f, 3.0e38f, 3.0e38f, 3.0e38f};
  int bi[4] = {0, 0, 0, 0};
#pragma unroll 4
  for (int m = 0; m < 256; m++) {
    float4 qq = s2[m];
#pragma unroll
    for (int q = 0; q < 4; q++) {
      float dx = px[q] - qq.x, dy = py[q] - qq.y, dz = pz[q] - qq.z;
      float d = fmaf(dz, dz, fmaf(dy, dy, dx * dx));  // EXACT contraction from passing rounds
      bool c = d < best[q];
      best[q] = c ? d : best[q];
      bi[q] = c ? m : bi[q];
    }
  }
#pragma unroll
  for (int q = 0; q < 4; q++) {
    int n = n0 + q * 256;
    cand[(size_t)mq * 65536 + (size_t)b * 8192 + n] =
        make_float2(best[q], __int_as_float(mq * 256 + bi[q]));
  }
}

// ---------------- GEMM1: 256o x 128p tile, fused argmin-combine, async swizzled staging ----------------
__global__ __launch_bounds__(512) void gemm1_k(const u16* __restrict__ w0b, const u16* __restrict__ f1t,
                                               const u16* __restrict__ f2t, const float2* __restrict__ cand,
                                               u16* __restrict__ y0) {
  __shared__ u16 As[256 * 64];  // 32KB, 16B-chunk XOR swizzle: phys_col = logical ^ (row&7)
  __shared__ u16 Bs[128 * 64];  // 16KB
  __shared__ int sidx[128];
  int t = threadIdx.x;
  int pt0 = blockIdx.x * 128;
  int b = pt0 >> 13;
  if (t < 128) {  // fused argmin combine over the 8 m-chunks
    int p = pt0 + t;
    float bd = 3.0e38f; int bi = 0;
#pragma unroll
    for (int qc = 0; qc < 8; qc++) {
      float2 c = cand[(size_t)qc * 65536 + p];
      if (c.x < bd) { bd = c.x; bi = __float_as_int(c.y); }  // strict <: lower chunk wins ties
    }
    sidx[t] = bi;
  }
  floatx4 zero = {0.f, 0.f, 0.f, 0.f};
  floatx4 acc[4][4];
#pragma unroll
  for (int i = 0; i < 4; i++)
#pragma unroll
    for (int j = 0; j < 4; j++) acc[i][j] = zero;
  int lane = t & 63, wave = t >> 6;
  int wrow = (wave >> 1) * 64, wcol = (wave & 1) * 64;
  int lr = lane & 15, lq = lane >> 4;
  int srow = lane >> 3;
  int sch = ((lane & 7) ^ srow) * 8;
  __syncthreads();
  int prow[2], gidx[2];
#pragma unroll
  for (int i = 0; i < 2; i++) {
    prow[i] = (wave * 2 + i) * 8 + srow;
    gidx[i] = sidx[prow[i]];
  }

#pragma unroll
  for (int k0 = 0; k0 < 384; k0 += 64) {
    __syncthreads();
#pragma unroll
    for (int i = 0; i < 4; i++) {
      int chunkA = wave * 4 + i;
      glds16(w0b + (size_t)(chunkA * 8 + srow) * 384 + k0 + sch, &As[chunkA * 512]);
    }
    if (k0 < 128) {
#pragma unroll
      for (int i = 0; i < 2; i++)
        glds16(f1t + (size_t)(pt0 + prow[i]) * 128 + k0 + sch, &Bs[(wave * 2 + i) * 512]);
    } else {
#pragma unroll
      for (int i = 0; i < 2; i++)
        glds16(f2t + ((size_t)(b << 11) + gidx[i]) * 256 + (k0 - 128) + sch, &Bs[(wave * 2 + i) * 512]);
    }
    __syncthreads();
#pragma unroll
    for (int ks = 0; ks < 2; ks++) {
      short8 af[4], bf[4];
#pragma unroll
      for (int i = 0; i < 4; i++) {
        int row = wrow + i * 16 + lr;
        af[i] = *(const short8*)&As[row * 64 + ((((ks << 2) | lq) ^ (lr & 7)) << 3)];
      }
#pragma unroll
      for (int j = 0; j < 4; j++) {
        int row = wcol + j * 16 + lr;
        bf[j] = *(const short8*)&Bs[row * 64 + ((((ks << 2) | lq) ^ (lr & 7)) << 3)];
      }
#pragma unroll
      for (int i = 0; i < 4; i++)
#pragma unroll
        for (int j = 0; j < 4; j++)
          acc[i][j] = __builtin_amdgcn_mfma_f32_16x16x32_bf16(af[i], bf[j], acc[i][j], 0, 0, 0);
    }
  }
#pragma unroll
  for (int i = 0; i < 4; i++) {
#pragma unroll
    for (int j = 0; j < 4; j++) {
      int o = wrow + i * 16 + lq * 4;
      int p = pt0 + wcol + j * 16 + lr;
      uint2 pk;
      pk.x = (u32)f2b(acc[i][j][0]) | ((u32)f2b(acc[i][j][1]) << 16);
      pk.y = (u32)f2b(acc[i][j][2]) | ((u32)f2b(acc[i][j][3]) << 16);
      *(uint2*)&y0[(size_t)p * 256 + o] = pk;
    }
  }
}

// ---------------- GEMM2: 256o x 128p tile, fused BN0 params + BN0/ReLU on the fly ----------------
__global__ __launch_bounds__(512) void gemm2_k(const u16* __restrict__ w1b, const u16* __restrict__ y0,
                                               const float* __restrict__ sum0, const float* __restrict__ sq0,
                                               const float* __restrict__ gamma0, const float* __restrict__ beta0,
                                               u16* __restrict__ y1) {
  __shared__ u16 As[256 * 64];   // async swizzled (32KB)
  __shared__ u16 Bs[128 * 72];   // register-staged (BN transform), padded (18KB)
  __shared__ float ssc[256], ssh[256];
  int t = threadIdx.x;
  if (t < 256) {  // fused bnparam0
    float mean = sum0[t] * (1.f / 65536.f);
    float var = fmaxf(sq0[t] * (1.f / 65536.f) - mean * mean, 0.f);
    float r = rsqrtf(var + 1e-5f);
    float sc = gamma0[t] * r;
    ssc[t] = sc;
    ssh[t] = beta0[t] - mean * sc;
  }
  int pt0 = blockIdx.x * 128;
  floatx4 zero = {0.f, 0.f, 0.f, 0.f};
  floatx4 acc[4][4];
#pragma unroll
  for (int i = 0; i < 4; i++)
#pragma unroll
    for (int j = 0; j < 4; j++) acc[i][j] = zero;
  int lane = t & 63, wave = t >> 6;
  int wrow = (wave >> 1) * 64, wcol = (wave & 1) * 64;
  int lr = lane & 15, lq = lane >> 4;
  int srow = lane >> 3;
  int sch = ((lane & 7) ^ srow) * 8;

#pragma unroll
  for (int k0 = 0; k0 < 256; k0 += 64) {
    __syncthreads();
#pragma unroll
    for (int i = 0; i < 4; i++) {
      int chunkA = wave * 4 + i;
      glds16(w1b + (size_t)(chunkA * 8 + srow) * 256 + k0 + sch, &As[chunkA * 512]);
    }
#pragma unroll
    for (int i = 0; i < 2; i++) {
      int id = t + i * 512;
      int row = id >> 3, ch = (id & 7) * 8;
      uint4 raw = *(const uint4*)(y0 + (size_t)(pt0 + row) * 256 + k0 + ch);
      u32 rw[4] = {raw.x, raw.y, raw.z, raw.w};
      u32 ow[4];
#pragma unroll
      for (int w = 0; w < 4; w++) {
        int k = k0 + ch + w * 2;
        float v0 = b2f((u16)(rw[w] & 0xffffu));
        float v1 = b2f((u16)(rw[w] >> 16));
        v0 = fmaxf(v0 * ssc[k] + ssh[k], 0.f);
        v1 = fmaxf(v1 * ssc[k + 1] + ssh[k + 1], 0.f);
        ow[w] = (u32)f2b(v0) | ((u32)f2b(v1) << 16);
      }
      uint4 ov; ov.x = ow[0]; ov.y = ow[1]; ov.z = ow[2]; ov.w = ow[3];
      *(uint4*)&Bs[row * 72 + ch] = ov;
    }
    __syncthreads();
#pragma unroll
    for (int ks = 0; ks < 2; ks++) {
      int kk = ks * 32 + lq * 8;
      short8 af[4], bf[4];
#pragma unroll
      for (int i = 0; i < 4; i++) {
        int row = wrow + i * 16 + lr;
        af[i] = *(const short8*)&As[row * 64 + ((((ks << 2) | lq) ^ (lr & 7)) << 3)];
      }
#pragma unroll
      for (int j = 0; j < 4; j++) bf[j] = *(const short8*)&Bs[(wcol + j * 16 + lr) * 72 + kk];
#pragma unroll
      for (int i = 0; i < 4; i++)
#pragma unroll
        for (int j = 0; j < 4; j++)
          acc[i][j] = __builtin_amdgcn_mfma_f32_16x16x32_bf16(af[i], bf[j], acc[i][j], 0, 0, 0);
    }
  }
#pragma unroll
  for (int i = 0; i < 4; i++) {
#pragma unroll
    for (int j = 0; j < 4; j++) {
      int o = wrow + i * 16 + lq * 4;
      int p = pt0 + wcol + j * 16 + lr;
      uint2 pk;
      pk.x = (u32)f2b(acc[i][j][0]) | ((u32)f2b(acc[i][j][1]) << 16);
      pk.y = (u32)f2b(acc[i][j][2]) | ((u32)f2b(acc[i][j][3]) << 16);
      *(uint2*)&y1[(size_t)p * 256 + o] = pk;
    }
  }
}

// ---------------- per-channel sums, coalesced uint4 reads ----------------
__global__ void stats_k(const u16* __restrict__ y, float* __restrict__ sum, float* __restrict__ sq) {
  __shared__ float ls[8][256];
  __shared__ float lqd[8][256];
  int t = threadIdx.x;
  int c8 = (t & 31) * 8;
  int p0 = t >> 5;
  float s[8] = {0.f, 0.f, 0.f, 0.f, 0.f, 0.f, 0.f, 0.f};
  float q[8] = {0.f, 0.f, 0.f, 0.f, 0.f, 0.f, 0.f, 0.f};
  const u16* base = y + (size_t)blockIdx.x * 65536;
  for (int it = 0; it < 32; it++) {
    int p = p0 + it * 8;
    uint4 raw = *(const uint4*)(base + (size_t)p * 256 + c8);
    u32 rw[4] = {raw.x, raw.y, raw.z, raw.w};
#pragma unroll
    for (int w = 0; w < 4; w++) {
      float v0 = b2f((u16)(rw[w] & 0xffffu));
      float v1 = b2f((u16)(rw[w] >> 16));
      s[w * 2] += v0;     q[w * 2] += v0 * v0;
      s[w * 2 + 1] += v1; q[w * 2 + 1] += v1 * v1;
    }
  }
#pragma unroll
  for (int e = 0; e < 8; e++) { ls[p0][c8 + e] = s[e]; lqd[p0][c8 + e] = q[e]; }
  __syncthreads();
  if (t < 256) {
    float ss = 0.f, qq = 0.f;
#pragma unroll
    for (int r = 0; r < 8; r++) { ss += ls[r][t]; qq += lqd[r][t]; }
    atomicAdd(&sum[t], ss);
    atomicAdd(&sq[t], qq);
  }
}

// ---------------- finalize: fused BN1 params + BN1+ReLU + transpose -> [b][o][n] fp32 ----------------
__global__ void finalize_k(const u16* __restrict__ y1, const float* __restrict__ sum1,
                           const float* __restrict__ sq1, const float* __restrict__ gamma1,
                           const float* __restrict__ beta1, float* __restrict__ out) {
  __shared__ float tile[64][65];
  __shared__ float fs[64], fh[64];
  int b = blockIdx.z, o0 = blockIdx.y * 64, n0 = blockIdx.x * 64;
  int t = threadIdx.x;
  if (t < 64) {  // fused bnparam1 for this block's o-range
    int o = o0 + t;
    float mean = sum1[o] * (1.f / 65536.f);
    float var = fmaxf(sq1[o] * (1.f / 65536.f) - mean * mean, 0.f);
    float r = rsqrtf(var + 1e-5f);
    float sc = gamma1[o] * r;
    fs[t] = sc;
    fh[t] = beta1[o] - mean * sc;
  }
  __syncthreads();
  int pl = t >> 2, ch = (t & 3) * 16;
  const u16* src = y1 + ((size_t)(b * 8192 + n0 + pl)) * 256 + o0 + ch;
  uint4 r0 = *(const uint4*)src;
  uint4 r1 = *(const uint4*)(src + 8);
  u16 hv[16];
  *(uint4*)&hv[0] = r0;
  *(uint4*)&hv[8] = r1;
#pragma unroll
  for (int e = 0; e < 16; e++) {
    float v = b2f(hv[e]) * fs[ch + e] + fh[ch + e];
    tile[pl][ch + e] = fmaxf(v, 0.f);
  }
  __syncthreads();
  int ol = t >> 2, nch = (t & 3) * 16;
  float* dst = out + ((size_t)(b * 256 + o0 + ol)) * 8192 + n0 + nch;
#pragma unroll
  for (int j = 0; j < 16; j += 4) {
    float4 v = make_float4(tile[nch + j][ol], tile[nch + j + 1][ol],
                           tile[nch + j + 2][ol], tile[nch + j + 3][ol]);
    *(float4*)(dst + j) = v;
  }
}

extern "C" void kernel_launch(void* const* d_in, const int* in_sizes, int n_in,
                              void* d_out, int out_size, void* d_ws, size_t ws_size,
                              hipStream_t stream) {
  const float* xyz1      = (const float*)d_in[0];
  const float* xyz2      = (const float*)d_in[1];
  const float* features1 = (const float*)d_in[2];
  const float* features2 = (const float*)d_in[3];
  const float* conv_w0   = (const float*)d_in[4];
  const float* gamma0    = (const float*)d_in[5];
  const float* beta0     = (const float*)d_in[6];
  const float* conv_w1   = (const float*)d_in[7];
  const float* gamma1    = (const float*)d_in[8];
  const float* beta1     = (const float*)d_in[9];
  float* out = (float*)d_out;

  char* ws = (char*)d_ws;
  size_t off = 0;
  auto alloc = [&](size_t bytes) {
    char* p = ws + off;
    off = (off + bytes + 4095) & ~(size_t)4095;
    return p;
  };
  float*  sums = (float*)alloc(4 * 256 * 4);            // sum0, sq0, sum1, sq1
  u16*    w0b  = (u16*)alloc(256 * 384 * 2);
  u16*    w1b  = (u16*)alloc(256 * 256 * 2);
  float2* cand = (float2*)alloc((size_t)8 * 65536 * 8); // 4MB, own allocation (read by gemm1)
  u16*    f1t  = (u16*)alloc((size_t)65536 * 128 * 2);
  u16*    f2t  = (u16*)alloc((size_t)16384 * 256 * 2);
  u16*    y0   = (u16*)alloc((size_t)65536 * 256 * 2);
  u16*    y1   = (u16*)alloc((size_t)65536 * 256 * 2);

  prep_k<<<dim3(640), 256, 0, stream>>>(conv_w0, conv_w1, w0b, w1b, sums);
  argmin_part_k<<<dim3(8, 8, 8), 256, 0, stream>>>(xyz1, xyz2, cand);
  transpose_cast_k<<<dim3(128, 2, 8), 256, 0, stream>>>(features1, f1t, 128, 8192);
  transpose_cast_k<<<dim3(32, 4, 8), 256, 0, stream>>>(features2, f2t, 256, 2048);
  gemm1_k<<<dim3(512), 512, 0, stream>>>(w0b, f1t, f2t, cand, y0);
  stats_k<<<dim3(256), 256, 0, stream>>>(y0, sums + 0, sums + 256);
  gemm2_k<<<dim3(512), 512, 0, stream>>>(w1b, y0, sums + 0, sums + 256, gamma0, beta0, y1);
  stats_k<<<dim3(256), 256, 0, stream>>>(y1, sums + 512, sums + 768);
  finalize_k<<<dim3(128, 4, 8), 256, 0, stream>>>(y1, sums + 512, sums + 768, gamma1, beta1, out);
}

// Round 4
// 243.320 us; speedup vs baseline: 1.1279x; 1.0269x over previous
//
#include <hip/hip_runtime.h>
#include <stdint.h>

typedef unsigned short u16;
typedef unsigned int u32;
typedef __attribute__((ext_vector_type(8))) short short8;
typedef __attribute__((ext_vector_type(4))) float floatx4;

__device__ __forceinline__ u16 f2b(float f) {
  union { float f; u32 u; } c; c.f = f;
  u32 u = c.u;
  u += 0x7fffu + ((u >> 16) & 1u);
  return (u16)(u >> 16);
}
__device__ __forceinline__ float b2f(u16 h) {
  union { u32 u; float f; } c; c.u = ((u32)h) << 16;
  return c.f;
}

// async global->LDS, 16B per lane; LDS dest is wave-uniform base + lane*16
__device__ __forceinline__ void glds16(const void* g, void* l) {
  __builtin_amdgcn_global_load_lds((__attribute__((address_space(1))) void*)g,
                                   (__attribute__((address_space(3))) void*)l, 16, 0, 0);
}

// ---------------- mega-prep: argmin parts | transposes | weight casts | zero sums ----------------
// blocks [0,512): argmin  [512,2560): f1 transpose  [2560,3584): f2 transpose  [3584,4224): casts+zero
__global__ void prep_all_k(const float* __restrict__ xyz1, const float* __restrict__ xyz2,
                           float2* __restrict__ cand,
                           const float* __restrict__ f1, u16* __restrict__ f1t,
                           const float* __restrict__ f2, u16* __restrict__ f2t,
                           const float* __restrict__ w0, u16* __restrict__ w0b,
                           const float* __restrict__ w1, u16* __restrict__ w1b,
                           float* __restrict__ sums) {
  __shared__ __align__(16) char smem[9216];
  int blk = blockIdx.x, t = threadIdx.x;
  if (blk < 512) {
    // ---- argmin: 4 query points/thread, one 256-chunk of M ----
    float4* s2 = (float4*)smem;
    int nq = blk & 7, mq = (blk >> 3) & 7, b = blk >> 6;
    const float* x2 = xyz2 + ((size_t)b * 2048 + mq * 256) * 3;
    s2[t] = make_float4(x2[t * 3], x2[t * 3 + 1], x2[t * 3 + 2], 0.f);
    __syncthreads();
    int n0 = nq * 1024 + t;
    float px[4], py[4], pz[4];
#pragma unroll
    for (int q = 0; q < 4; q++) {
      const float* p1 = xyz1 + ((size_t)b * 8192 + n0 + q * 256) * 3;
      px[q] = p1[0]; py[q] = p1[1]; pz[q] = p1[2];
    }
    float best[4] = {3.0e38f, 3.0e38f, 3.0e38f, 3.0e38f};
    int bi[4] = {0, 0, 0, 0};
#pragma unroll 4
    for (int m = 0; m < 256; m++) {
      float4 qq = s2[m];
#pragma unroll
      for (int q = 0; q < 4; q++) {
        float dx = px[q] - qq.x, dy = py[q] - qq.y, dz = pz[q] - qq.z;
        float d = fmaf(dz, dz, fmaf(dy, dy, dx * dx));  // EXACT contraction from passing rounds
        bool c = d < best[q];
        best[q] = c ? d : best[q];
        bi[q] = c ? m : bi[q];
      }
    }
#pragma unroll
    for (int q = 0; q < 4; q++) {
      int n = n0 + q * 256;
      cand[(size_t)mq * 65536 + (size_t)b * 8192 + n] =
          make_float2(best[q], __int_as_float(mq * 256 + bi[q]));
    }
  } else if (blk < 3584) {
    // ---- tiled transpose+cast [B][C][N] fp32 -> [B][N][C] bf16 ----
    const float* in; u16* out; int C, N, bx, by, bz;
    if (blk < 2560) { int rel = blk - 512;  in = f1; out = f1t; C = 128; N = 8192; bx = rel & 127; by = (rel >> 7) & 1; bz = rel >> 8; }
    else            { int rel = blk - 2560; in = f2; out = f2t; C = 256; N = 2048; bx = rel & 31;  by = (rel >> 5) & 3; bz = rel >> 7; }
    u16 (*tile)[72] = (u16(*)[72])smem;
    int c0 = by * 64, n0 = bx * 64;
    const float* src = in + ((size_t)bz * C + c0) * N + n0;
#pragma unroll
    for (int i = 0; i < 4; i++) {
      int id = t + i * 256;
      int c = id >> 4, nq = (id & 15) * 4;
      float4 v = *(const float4*)(src + (size_t)c * N + nq);
      tile[nq + 0][c] = f2b(v.x);
      tile[nq + 1][c] = f2b(v.y);
      tile[nq + 2][c] = f2b(v.z);
      tile[nq + 3][c] = f2b(v.w);
    }
    __syncthreads();
    int n = t >> 2, ch = (t & 3) * 16;
    u16* dst = out + ((size_t)bz * N + n0 + n) * C + c0 + ch;
    *(uint4*)dst = *(const uint4*)&tile[n][ch];
    *(uint4*)(dst + 8) = *(const uint4*)&tile[n][ch + 8];
  } else {
    // ---- weight casts + zero stats ----
    int rel = blk - 3584;
    int i = rel * 256 + t;
    if (rel < 384) w0b[i] = f2b(w0[i]);
    else { int j = i - 98304; w1b[j] = f2b(w1[j]); }
    if (rel < 4) sums[i] = 0.f;
  }
}

// ---------------- GEMM1: 256o x 128p tile, fused argmin-combine + stats0 epilogue ----------------
__global__ __launch_bounds__(512) void gemm1_k(const u16* __restrict__ w0b, const u16* __restrict__ f1t,
                                               const u16* __restrict__ f2t, const float2* __restrict__ cand,
                                               float* __restrict__ sum0, float* __restrict__ sq0,
                                               u16* __restrict__ y0) {
  __shared__ u16 As[256 * 64];  // 32KB, 16B-chunk XOR swizzle: phys_col = logical ^ (row&7)
  __shared__ u16 Bs[128 * 64];  // 16KB
  __shared__ int sidx[128];
  int t = threadIdx.x;
  int pt0 = blockIdx.x * 128;
  int b = pt0 >> 13;
  if (t < 128) {  // fused argmin combine over the 8 m-chunks
    int p = pt0 + t;
    float bd = 3.0e38f; int bi = 0;
#pragma unroll
    for (int qc = 0; qc < 8; qc++) {
      float2 c = cand[(size_t)qc * 65536 + p];
      if (c.x < bd) { bd = c.x; bi = __float_as_int(c.y); }  // strict <: lower chunk wins ties
    }
    sidx[t] = bi;
  }
  floatx4 zero = {0.f, 0.f, 0.f, 0.f};
  floatx4 acc[4][4];
#pragma unroll
  for (int i = 0; i < 4; i++)
#pragma unroll
    for (int j = 0; j < 4; j++) acc[i][j] = zero;
  int lane = t & 63, wave = t >> 6;
  int wrow = (wave >> 1) * 64, wcol = (wave & 1) * 64;
  int lr = lane & 15, lq = lane >> 4;
  int srow = lane >> 3;
  int sch = ((lane & 7) ^ srow) * 8;
  __syncthreads();
  int prow[2], gidx[2];
#pragma unroll
  for (int i = 0; i < 2; i++) {
    prow[i] = (wave * 2 + i) * 8 + srow;
    gidx[i] = sidx[prow[i]];
  }

#pragma unroll
  for (int k0 = 0; k0 < 384; k0 += 64) {
    __syncthreads();
#pragma unroll
    for (int i = 0; i < 4; i++) {
      int chunkA = wave * 4 + i;
      glds16(w0b + (size_t)(chunkA * 8 + srow) * 384 + k0 + sch, &As[chunkA * 512]);
    }
    if (k0 < 128) {
#pragma unroll
      for (int i = 0; i < 2; i++)
        glds16(f1t + (size_t)(pt0 + prow[i]) * 128 + k0 + sch, &Bs[(wave * 2 + i) * 512]);
    } else {
#pragma unroll
      for (int i = 0; i < 2; i++)
        glds16(f2t + ((size_t)(b << 11) + gidx[i]) * 256 + (k0 - 128) + sch, &Bs[(wave * 2 + i) * 512]);
    }
    __syncthreads();
#pragma unroll
    for (int ks = 0; ks < 2; ks++) {
      short8 af[4], bf[4];
#pragma unroll
      for (int i = 0; i < 4; i++) {
        int row = wrow + i * 16 + lr;
        af[i] = *(const short8*)&As[row * 64 + ((((ks << 2) | lq) ^ (lr & 7)) << 3)];
      }
#pragma unroll
      for (int j = 0; j < 4; j++) {
        int row = wcol + j * 16 + lr;
        bf[j] = *(const short8*)&Bs[row * 64 + ((((ks << 2) | lq) ^ (lr & 7)) << 3)];
      }
#pragma unroll
      for (int i = 0; i < 4; i++)
#pragma unroll
        for (int j = 0; j < 4; j++)
          acc[i][j] = __builtin_amdgcn_mfma_f32_16x16x32_bf16(af[i], bf[j], acc[i][j], 0, 0, 0);
    }
  }
  // y0 stores
#pragma unroll
  for (int i = 0; i < 4; i++) {
#pragma unroll
    for (int j = 0; j < 4; j++) {
      int o = wrow + i * 16 + lq * 4;
      int p = pt0 + wcol + j * 16 + lr;
      uint2 pk;
      pk.x = (u32)f2b(acc[i][j][0]) | ((u32)f2b(acc[i][j][1]) << 16);
      pk.y = (u32)f2b(acc[i][j][2]) | ((u32)f2b(acc[i][j][3]) << 16);
      *(uint2*)&y0[(size_t)p * 256 + o] = pk;
    }
  }
  // fused stats0: per-block partial (sum, sumsq) per channel from fp32 accs
  __syncthreads();                 // all waves done reading As
  float* red = (float*)As;         // alias dead A-tile: red[0..255]=sum, [256..511]=sq
  red[t] = 0.f;
  __syncthreads();
#pragma unroll
  for (int i = 0; i < 4; i++) {
#pragma unroll
    for (int r = 0; r < 4; r++) {
      float s = acc[i][0][r] + acc[i][1][r] + acc[i][2][r] + acc[i][3][r];
      float q = acc[i][0][r] * acc[i][0][r] + acc[i][1][r] * acc[i][1][r] +
                acc[i][2][r] * acc[i][2][r] + acc[i][3][r] * acc[i][3][r];
#pragma unroll
      for (int m = 8; m >= 1; m >>= 1) { s += __shfl_xor(s, m); q += __shfl_xor(q, m); }
      if (lr == 0) {
        int o = wrow + i * 16 + lq * 4 + r;
        atomicAdd(&red[o], s);
        atomicAdd(&red[256 + o], q);
      }
    }
  }
  __syncthreads();
  if (t < 256) {
    atomicAdd(&sum0[t], red[t]);
    atomicAdd(&sq0[t], red[256 + t]);
  }
}

// ---------------- GEMM2: fused BN0 params + BN0/ReLU on the fly + stats1 epilogue ----------------
__global__ __launch_bounds__(512) void gemm2_k(const u16* __restrict__ w1b, const u16* __restrict__ y0,
                                               const float* __restrict__ sum0, const float* __restrict__ sq0,
                                               const float* __restrict__ gamma0, const float* __restrict__ beta0,
                                               float* __restrict__ sum1, float* __restrict__ sq1,
                                               u16* __restrict__ y1) {
  __shared__ u16 As[256 * 64];   // async swizzled (32KB)
  __shared__ u16 Bs[128 * 72];   // register-staged (BN transform), padded (18KB)
  __shared__ float ssc[256], ssh[256];
  int t = threadIdx.x;
  if (t < 256) {  // fused bnparam0
    float mean = sum0[t] * (1.f / 65536.f);
    float var = fmaxf(sq0[t] * (1.f / 65536.f) - mean * mean, 0.f);
    float r = rsqrtf(var + 1e-5f);
    float sc = gamma0[t] * r;
    ssc[t] = sc;
    ssh[t] = beta0[t] - mean * sc;
  }
  int pt0 = blockIdx.x * 128;
  floatx4 zero = {0.f, 0.f, 0.f, 0.f};
  floatx4 acc[4][4];
#pragma unroll
  for (int i = 0; i < 4; i++)
#pragma unroll
    for (int j = 0; j < 4; j++) acc[i][j] = zero;
  int lane = t & 63, wave = t >> 6;
  int wrow = (wave >> 1) * 64, wcol = (wave & 1) * 64;
  int lr = lane & 15, lq = lane >> 4;
  int srow = lane >> 3;
  int sch = ((lane & 7) ^ srow) * 8;

#pragma unroll
  for (int k0 = 0; k0 < 256; k0 += 64) {
    __syncthreads();
#pragma unroll
    for (int i = 0; i < 4; i++) {
      int chunkA = wave * 4 + i;
      glds16(w1b + (size_t)(chunkA * 8 + srow) * 256 + k0 + sch, &As[chunkA * 512]);
    }
#pragma unroll
    for (int i = 0; i < 2; i++) {
      int id = t + i * 512;
      int row = id >> 3, ch = (id & 7) * 8;
      uint4 raw = *(const uint4*)(y0 + (size_t)(pt0 + row) * 256 + k0 + ch);
      u32 rw[4] = {raw.x, raw.y, raw.z, raw.w};
      u32 ow[4];
#pragma unroll
      for (int w = 0; w < 4; w++) {
        int k = k0 + ch + w * 2;
        float v0 = b2f((u16)(rw[w] & 0xffffu));
        float v1 = b2f((u16)(rw[w] >> 16));
        v0 = fmaxf(v0 * ssc[k] + ssh[k], 0.f);
        v1 = fmaxf(v1 * ssc[k + 1] + ssh[k + 1], 0.f);
        ow[w] = (u32)f2b(v0) | ((u32)f2b(v1) << 16);
      }
      uint4 ov; ov.x = ow[0]; ov.y = ow[1]; ov.z = ow[2]; ov.w = ow[3];
      *(uint4*)&Bs[row * 72 + ch] = ov;
    }
    __syncthreads();
#pragma unroll
    for (int ks = 0; ks < 2; ks++) {
      int kk = ks * 32 + lq * 8;
      short8 af[4], bf[4];
#pragma unroll
      for (int i = 0; i < 4; i++) {
        int row = wrow + i * 16 + lr;
        af[i] = *(const short8*)&As[row * 64 + ((((ks << 2) | lq) ^ (lr & 7)) << 3)];
      }
#pragma unroll
      for (int j = 0; j < 4; j++) bf[j] = *(const short8*)&Bs[(wcol + j * 16 + lr) * 72 + kk];
#pragma unroll
      for (int i = 0; i < 4; i++)
#pragma unroll
        for (int j = 0; j < 4; j++)
          acc[i][j] = __builtin_amdgcn_mfma_f32_16x16x32_bf16(af[i], bf[j], acc[i][j], 0, 0, 0);
    }
  }
#pragma unroll
  for (int i = 0; i < 4; i++) {
#pragma unroll
    for (int j = 0; j < 4; j++) {
      int o = wrow + i * 16 + lq * 4;
      int p = pt0 + wcol + j * 16 + lr;
      uint2 pk;
      pk.x = (u32)f2b(acc[i][j][0]) | ((u32)f2b(acc[i][j][1]) << 16);
      pk.y = (u32)f2b(acc[i][j][2]) | ((u32)f2b(acc[i][j][3]) << 16);
      *(uint2*)&y1[(size_t)p * 256 + o] = pk;
    }
  }
  // fused stats1
  __syncthreads();
  float* red = (float*)As;
  red[t] = 0.f;
  __syncthreads();
#pragma unroll
  for (int i = 0; i < 4; i++) {
#pragma unroll
    for (int r = 0; r < 4; r++) {
      float s = acc[i][0][r] + acc[i][1][r] + acc[i][2][r] + acc[i][3][r];
      float q = acc[i][0][r] * acc[i][0][r] + acc[i][1][r] * acc[i][1][r] +
                acc[i][2][r] * acc[i][2][r] + acc[i][3][r] * acc[i][3][r];
#pragma unroll
      for (int m = 8; m >= 1; m >>= 1) { s += __shfl_xor(s, m); q += __shfl_xor(q, m); }
      if (lr == 0) {
        int o = wrow + i * 16 + lq * 4 + r;
        atomicAdd(&red[o], s);
        atomicAdd(&red[256 + o], q);
      }
    }
  }
  __syncthreads();
  if (t < 256) {
    atomicAdd(&sum1[t], red[t]);
    atomicAdd(&sq1[t], red[256 + t]);
  }
}

// ---------------- finalize: fused BN1 params + BN1+ReLU + transpose -> [b][o][n] fp32 ----------------
__global__ void finalize_k(const u16* __restrict__ y1, const float* __restrict__ sum1,
                           const float* __restrict__ sq1, const float* __restrict__ gamma1,
                           const float* __restrict__ beta1, float* __restrict__ out) {
  __shared__ float tile[64][65];
  __shared__ float fs[64], fh[64];
  int b = blockIdx.z, o0 = blockIdx.y * 64, n0 = blockIdx.x * 64;
  int t = threadIdx.x;
  if (t < 64) {
    int o = o0 + t;
    float mean = sum1[o] * (1.f / 65536.f);
    float var = fmaxf(sq1[o] * (1.f / 65536.f) - mean * mean, 0.f);
    float r = rsqrtf(var + 1e-5f);
    float sc = gamma1[o] * r;
    fs[t] = sc;
    fh[t] = beta1[o] - mean * sc;
  }
  __syncthreads();
  int pl = t >> 2, ch = (t & 3) * 16;
  const u16* src = y1 + ((size_t)(b * 8192 + n0 + pl)) * 256 + o0 + ch;
  uint4 r0 = *(const uint4*)src;
  uint4 r1 = *(const uint4*)(src + 8);
  u16 hv[16];
  *(uint4*)&hv[0] = r0;
  *(uint4*)&hv[8] = r1;
#pragma unroll
  for (int e = 0; e < 16; e++) {
    float v = b2f(hv[e]) * fs[ch + e] + fh[ch + e];
    tile[pl][ch + e] = fmaxf(v, 0.f);
  }
  __syncthreads();
  int ol = t >> 2, nch = (t & 3) * 16;
  float* dst = out + ((size_t)(b * 256 + o0 + ol)) * 8192 + n0 + nch;
#pragma unroll
  for (int j = 0; j < 16; j += 4) {
    float4 v = make_float4(tile[nch + j][ol], tile[nch + j + 1][ol],
                           tile[nch + j + 2][ol], tile[nch + j + 3][ol]);
    *(float4*)(dst + j) = v;
  }
}

extern "C" void kernel_launch(void* const* d_in, const int* in_sizes, int n_in,
                              void* d_out, int out_size, void* d_ws, size_t ws_size,
                              hipStream_t stream) {
  const float* xyz1      = (const float*)d_in[0];
  const float* xyz2      = (const float*)d_in[1];
  const float* features1 = (const float*)d_in[2];
  const float* features2 = (const float*)d_in[3];
  const float* conv_w0   = (const float*)d_in[4];
  const float* gamma0    = (const float*)d_in[5];
  const float* beta0     = (const float*)d_in[6];
  const float* conv_w1   = (const float*)d_in[7];
  const float* gamma1    = (const float*)d_in[8];
  const float* beta1     = (const float*)d_in[9];
  float* out = (float*)d_out;

  char* ws = (char*)d_ws;
  size_t off = 0;
  auto alloc = [&](size_t bytes) {
    char* p = ws + off;
    off = (off + bytes + 4095) & ~(size_t)4095;
    return p;
  };
  float*  sums = (float*)alloc(4 * 256 * 4);            // sum0, sq0, sum1, sq1
  u16*    w0b  = (u16*)alloc(256 * 384 * 2);
  u16*    w1b  = (u16*)alloc(256 * 256 * 2);
  float2* cand = (float2*)alloc((size_t)8 * 65536 * 8); // 4MB
  u16*    f1t  = (u16*)alloc((size_t)65536 * 128 * 2);
  u16*    f2t  = (u16*)alloc((size_t)16384 * 256 * 2);
  u16*    y0   = (u16*)alloc((size_t)65536 * 256 * 2);
  u16*    y1   = (u16*)alloc((size_t)65536 * 256 * 2);

  prep_all_k<<<dim3(4224), 256, 0, stream>>>(xyz1, xyz2, cand, features1, f1t,
                                             features2, f2t, conv_w0, w0b, conv_w1, w1b, sums);
  gemm1_k<<<dim3(512), 512, 0, stream>>>(w0b, f1t, f2t, cand, sums + 0, sums + 256, y0);
  gemm2_k<<<dim3(512), 512, 0, stream>>>(w1b, y0, sums + 0, sums + 256, gamma0, beta0,
                                         sums + 512, sums + 768, y1);
  finalize_k<<<dim3(128, 4, 8), 256, 0, stream>>>(y1, sums + 512, sums + 768, gamma1, beta1, out);
}